// Round 1
// baseline (135.239 us; speedup 1.0000x reference)
//
#include <hip/hip_runtime.h>
#include <math.h>

// Problem: B=8, G=2048, K=32, N=64.
// Key simplification (verified algebraically): e_x is constant along the K
// axis that up/down average over => k_anp_x = mean(ff,K) exactly, so the
// whole std_dev/p/nrm/lc/e_x branch is dead code. kl = 2*mean(ff,K), and the
// subsequent norm over G cancels the factor 2: kl_n = M / ||M||_G.
//
// Pipeline:
//  K1/K1b: global std(diff, ddof=1) (two-stage deterministic double reduce)
//  K2    : per (b,g,k) row: knn_line(68) @ fourier_B(68x32), sincos,
//          mean over K -> M[b,g,c]  (B*G*64 floats in ws)
//  K3a   : inv_r[b,c] = 1/||M[b,:,c]||  (norm over G)
//  K3b   : out[b,c,g]    = gelu(M*inv_r) - lc_line   (c<64)
//          out[b,64+c,g] = lc_line                    (lc_line = lc/||lc||_N)

constexpr int Gg = 2048;
constexpr int Kk = 32;

// ws layout (bytes); total needed = 65536 + 4 MiB ≈ 4.26 MB
constexpr size_t PART_OFF = 0;       // 2048*2 doubles = 32768 B
constexpr size_t STD_OFF  = 32768;   // 1 float
constexpr size_t INVR_OFF = 33024;   // 512 floats
constexpr size_t M_OFF    = 65536;   // 8*2048*64 floats = 4 MiB

// ---------------- K1: partial sums for global std ----------------
__global__ __launch_bounds__(256) void k1_partial(const float4* __restrict__ knn4,
                                                  const float4* __restrict__ lc4,
                                                  double* __restrict__ part)
{
    int tid  = threadIdx.x;
    int base = blockIdx.x * 256 + tid;
    double s = 0.0, s2 = 0.0;
    #pragma unroll
    for (int i = 0; i < 16; ++i) {
        int idx = base + i * 524288;               // float4 index, 8388608 total
        float4 q = knn4[idx];
        float4 l = lc4[(idx >> 9) * 16 + (idx & 15)];  // row>>5 = idx>>9
        float d0 = q.x - l.x, d1 = q.y - l.y, d2 = q.z - l.z, d3 = q.w - l.w;
        s += (double)d0; s += (double)d1; s += (double)d2; s += (double)d3;
        s2 = fma((double)d0, (double)d0, s2);
        s2 = fma((double)d1, (double)d1, s2);
        s2 = fma((double)d2, (double)d2, s2);
        s2 = fma((double)d3, (double)d3, s2);
    }
    __shared__ double sh[512];
    sh[tid] = s; sh[256 + tid] = s2;
    __syncthreads();
    for (int off = 128; off > 0; off >>= 1) {
        if (tid < off) { sh[tid] += sh[tid + off]; sh[256 + tid] += sh[256 + tid + off]; }
        __syncthreads();
    }
    if (tid == 0) { part[blockIdx.x * 2] = sh[0]; part[blockIdx.x * 2 + 1] = sh[256]; }
}

__global__ __launch_bounds__(256) void k1_final(const double* __restrict__ part,
                                                float* __restrict__ stdp)
{
    int tid = threadIdx.x;
    double s = 0.0, s2 = 0.0;
    for (int i = tid; i < 2048; i += 256) { s += part[2*i]; s2 += part[2*i+1]; }
    __shared__ double sh[512];
    sh[tid] = s; sh[256 + tid] = s2;
    __syncthreads();
    for (int off = 128; off > 0; off >>= 1) {
        if (tid < off) { sh[tid] += sh[tid + off]; sh[256 + tid] += sh[256 + tid + off]; }
        __syncthreads();
    }
    if (tid == 0) {
        double S = sh[0], S2 = sh[256];
        double Mn = 33554432.0;
        double var = (S2 - S * S / Mn) / (Mn - 1.0);
        stdp[0] = (float)sqrt(var);
    }
}

// ---------------- K2: main fused kernel ----------------
__global__ __launch_bounds__(256) void k2_main(const float* __restrict__ knn,
                                               const float* __restrict__ lc,
                                               const float* __restrict__ fB,
                                               const float* __restrict__ stdp,
                                               float* __restrict__ M)
{
    const int tid   = threadIdx.x;
    const int row   = blockIdx.x * 256 + tid;   // (b*G+g)*K + k
    const int lcrow = row >> 5;
    const float inv = 1.0f / (stdp[0] + 1e-5f);

    const float4* kq = (const float4*)knn + (size_t)row * 16;
    const float4* lq = (const float4*)lc  + (size_t)lcrow * 16;

    float acc[32];
    #pragma unroll
    for (int c = 0; c < 32; ++c) acc[c] = 0.0f;

    // j4 = 0 peeled: capture raw lc[0..2] and normalized knn[0..2]
    float4 q0 = kq[0];
    float4 l0 = lq[0];
    float d0 = (q0.x - l0.x) * inv;
    float d1 = (q0.y - l0.y) * inv;
    float d2 = (q0.z - l0.z) * inv;
    float d3 = (q0.w - l0.w) * inv;
    float dot = d0 * l0.x;
    dot = fmaf(d1, l0.y, dot);
    dot = fmaf(d2, l0.z, dot);
    dot = fmaf(d3, l0.w, dot);
    float kn0 = d0, kn1 = d1, kn2 = d2;
    float ln0 = l0.x, ln1 = l0.y, ln2 = l0.z;
    {
        const float* fr = fB;
        #pragma unroll
        for (int c = 0; c < 32; ++c) acc[c] = fmaf(d0, fr[c],      acc[c]);
        #pragma unroll
        for (int c = 0; c < 32; ++c) acc[c] = fmaf(d1, fr[32 + c], acc[c]);
        #pragma unroll
        for (int c = 0; c < 32; ++c) acc[c] = fmaf(d2, fr[64 + c], acc[c]);
        #pragma unroll
        for (int c = 0; c < 32; ++c) acc[c] = fmaf(d3, fr[96 + c], acc[c]);
    }
    for (int j4 = 1; j4 < 16; ++j4) {
        float4 q = kq[j4];
        float4 l = lq[j4];
        float e0 = (q.x - l.x) * inv;
        float e1 = (q.y - l.y) * inv;
        float e2 = (q.z - l.z) * inv;
        float e3 = (q.w - l.w) * inv;
        dot = fmaf(e0, l.x, dot);
        dot = fmaf(e1, l.y, dot);
        dot = fmaf(e2, l.z, dot);
        dot = fmaf(e3, l.w, dot);
        const float* fr = fB + j4 * 128;
        #pragma unroll
        for (int c = 0; c < 32; ++c) acc[c] = fmaf(e0, fr[c],      acc[c]);
        #pragma unroll
        for (int c = 0; c < 32; ++c) acc[c] = fmaf(e1, fr[32 + c], acc[c]);
        #pragma unroll
        for (int c = 0; c < 32; ++c) acc[c] = fmaf(e2, fr[64 + c], acc[c]);
        #pragma unroll
        for (int c = 0; c < 32; ++c) acc[c] = fmaf(e3, fr[96 + c], acc[c]);
    }

    // descending sort3 of knn[0:3] (normalized) and lc[0:3] (raw)
    float a0 = kn0, a1 = kn1, a2 = kn2;
    float b0 = ln0, b1 = ln1, b2 = ln2;
    float t;
    if (a0 < a1) { t = a0; a0 = a1; a1 = t; }
    if (a1 < a2) { t = a1; a1 = a2; a2 = t; }
    if (a0 < a1) { t = a0; a0 = a1; a1 = t; }
    if (b0 < b1) { t = b0; b0 = b1; b1 = t; }
    if (b1 < b2) { t = b1; b1 = b2; b2 = t; }
    if (b0 < b1) { t = b0; b0 = b1; b1 = t; }

    // cross(a, b)
    float cr0 = a1 * b2 - a2 * b1;
    float cr1 = a2 * b0 - a0 * b2;
    float cr2 = a0 * b1 - a1 * b0;
    {
        const float* fr = fB + 64 * 32;
        #pragma unroll
        for (int c = 0; c < 32; ++c) acc[c] = fmaf(cr0, fr[c],      acc[c]);
        #pragma unroll
        for (int c = 0; c < 32; ++c) acc[c] = fmaf(cr1, fr[32 + c], acc[c]);
        #pragma unroll
        for (int c = 0; c < 32; ++c) acc[c] = fmaf(cr2, fr[64 + c], acc[c]);
        #pragma unroll
        for (int c = 0; c < 32; ++c) acc[c] = fmaf(dot, fr[96 + c], acc[c]);
    }

    // sincos + mean over K (32 lanes), stage in LDS, coalesced store
    __shared__ float red[8][64];
    #pragma unroll
    for (int c = 0; c < 32; ++c) {
        float ph = 6.28318530717958647692f * acc[c];
        float sv, cv;
        __sincosf(ph, &sv, &cv);
        #pragma unroll
        for (int m = 1; m <= 16; m <<= 1) {
            sv += __shfl_xor(sv, m);
            cv += __shfl_xor(cv, m);
        }
        if ((tid & 31) == 0) {
            red[tid >> 5][c]      = sv * (1.0f / 32.0f);
            red[tid >> 5][32 + c] = cv * (1.0f / 32.0f);
        }
    }
    __syncthreads();
    const int grp = tid >> 5;
    const int c2  = (tid & 31) * 2;
    const int mrow = blockIdx.x * 8 + grp;      // = b*G+g
    float2 v = make_float2(red[grp][c2], red[grp][c2 + 1]);
    *(float2*)(M + (size_t)mrow * 64 + c2) = v;
}

// ---------------- K3a: inv norm of M over G per (b,c) ----------------
__global__ __launch_bounds__(256) void k3_rnorm(const float* __restrict__ M,
                                                float* __restrict__ invr)
{
    int bc = blockIdx.x;                  // b*64 + c
    int b = bc >> 6, c = bc & 63;
    int tid = threadIdx.x;
    const float* base = M + ((size_t)b * Gg) * 64 + c;
    float ss = 0.0f;
    for (int g = tid; g < Gg; g += 256) {
        float v = base[(size_t)g * 64];
        ss = fmaf(v, v, ss);
    }
    #pragma unroll
    for (int m = 1; m <= 32; m <<= 1) ss += __shfl_xor(ss, m);
    __shared__ float sh[4];
    if ((tid & 63) == 0) sh[tid >> 6] = ss;
    __syncthreads();
    if (tid == 0) invr[bc] = 1.0f / sqrtf(sh[0] + sh[1] + sh[2] + sh[3]);
}

// ---------------- K3b: finalize ----------------
__global__ __launch_bounds__(256) void k3_final(const float* __restrict__ M,
                                                const float* __restrict__ lc,
                                                const float* __restrict__ invr,
                                                float* __restrict__ out)
{
    __shared__ float mt[64][65];
    __shared__ float lt[64][65];
    __shared__ float ir[64];
    __shared__ float iln[64];
    int tid = threadIdx.x;
    int b  = blockIdx.x >> 5;
    int g0 = (blockIdx.x & 31) * 64;
    if (tid < 64) ir[tid] = invr[b * 64 + tid];
    const float* Mb = M  + ((size_t)(b * Gg + g0)) * 64;
    const float* Lb = lc + ((size_t)(b * Gg + g0)) * 64;
    #pragma unroll
    for (int i = 0; i < 4; ++i) {
        int f = i * 1024 + tid * 4;
        int r = f >> 6, col = f & 63;
        float4 mv = *(const float4*)(Mb + f);
        float4 lv = *(const float4*)(Lb + f);
        mt[r][col] = mv.x; mt[r][col+1] = mv.y; mt[r][col+2] = mv.z; mt[r][col+3] = mv.w;
        lt[r][col] = lv.x; lt[r][col+1] = lv.y; lt[r][col+2] = lv.z; lt[r][col+3] = lv.w;
    }
    __syncthreads();
    if (tid < 64) {
        float ss = 0.0f;
        #pragma unroll
        for (int c = 0; c < 64; ++c) { float v = lt[tid][c]; ss = fmaf(v, v, ss); }
        iln[tid] = 1.0f / sqrtf(ss);
    }
    __syncthreads();
    int gl = tid & 63;
    int c0 = tid >> 6;                    // 0..3, wave-uniform
    float il = iln[gl];
    int obase = (b * 128) * Gg + g0 + gl;
    #pragma unroll
    for (int i = 0; i < 16; ++i) {
        int c = c0 + i * 4;
        float lcl = lt[gl][c] * il;
        float x = mt[gl][c] * ir[c];
        float kl = 0.5f * x * (1.0f + erff(x * 0.70710678118654752f));
        out[obase + c * Gg]        = kl - lcl;   // line_element
        out[obase + (c + 64) * Gg] = lcl;        // lc_line
    }
}

extern "C" void kernel_launch(void* const* d_in, const int* in_sizes, int n_in,
                              void* d_out, int out_size, void* d_ws, size_t ws_size,
                              hipStream_t stream)
{
    (void)in_sizes; (void)n_in; (void)out_size; (void)ws_size;
    const float* lc  = (const float*)d_in[0];   // (8,2048,64)
    const float* knn = (const float*)d_in[1];   // (8,2048,32,64)
    const float* fB  = (const float*)d_in[2];   // (68,32)
    float* out = (float*)d_out;                 // (8,128,2048) f32
    char* ws = (char*)d_ws;
    double* part = (double*)(ws + PART_OFF);
    float*  stdp = (float*)(ws + STD_OFF);
    float*  invr = (float*)(ws + INVR_OFF);
    float*  M    = (float*)(ws + M_OFF);

    hipLaunchKernelGGL(k1_partial, dim3(2048), dim3(256), 0, stream,
                       (const float4*)knn, (const float4*)lc, part);
    hipLaunchKernelGGL(k1_final, dim3(1), dim3(256), 0, stream, part, stdp);
    hipLaunchKernelGGL(k2_main, dim3(2048), dim3(256), 0, stream,
                       knn, lc, fB, stdp, M);
    hipLaunchKernelGGL(k3_rnorm, dim3(512), dim3(256), 0, stream, M, invr);
    hipLaunchKernelGGL(k3_final, dim3(256), dim3(256), 0, stream, M, lc, invr, out);
}